// Round 3
// baseline (9931.047 us; speedup 1.0000x reference)
//
#include <hip/hip_runtime.h>
#include <cstddef>
#include <cstdint>

#define T_STEPS 80
#define BATCH   256
#define DIM     4936
#define EMB     200
#define DE      5136
#define HID     512
#define SIXH    3072
#define FIVEH   2560
#define NCLS    151
#define NPACK   15504
#define NKT     156          // ceil(4936/32) -> Kpad = 4992

typedef unsigned short ushort_t;
typedef short short8 __attribute__((ext_vector_type(8)));
typedef float f32x4 __attribute__((ext_vector_type(4)));

__device__ inline ushort_t f2bf_rn(float x) {
    union { float f; uint32_t u; } v; v.f = x;
    uint32_t u = v.u;
    return (ushort_t)((u + 0x7FFFu + ((u >> 16) & 1u)) >> 16);
}
__device__ inline float bf2f(ushort_t b) {
    union { float f; uint32_t u; } v; v.u = ((uint32_t)b) << 16;
    return v.f;
}
__device__ inline float sigmoidf(float x) { return 1.f / (1.f + expf(-x)); }

// ---------------------------------------------------------------------------
// convert_split: src [ntiles*128 rows, ld] fp32 -> hi/lo bf16 in tiled layout
// out[tile][ktile][kb(4)][row(128)][8]   (zero-padded for k >= kvalid)
// ---------------------------------------------------------------------------
__global__ __launch_bounds__(256) void convert_split(
    const float* __restrict__ src, int ld, int kvalid,
    ushort_t* __restrict__ hi, ushort_t* __restrict__ lo, int nktiles)
{
    __shared__ float s[128][33];
    const int tid = threadIdx.x;
    const int kt  = blockIdx.x;
    const int mt  = blockIdx.y;

#pragma unroll
    for (int it = 0; it < 4; ++it) {
        int idx = it * 256 + tid;          // 1024 float4 slots
        int row = idx >> 3;
        int f4  = idx & 7;
        int k   = kt * 32 + f4 * 4;
        const float* p = src + (size_t)(mt * 128 + row) * ld + k;
        float4 v;
        if (k + 3 < kvalid) v = *(const float4*)p;
        else {
            v.x = (k + 0) < kvalid ? p[0] : 0.f;
            v.y = (k + 1) < kvalid ? p[1] : 0.f;
            v.z = (k + 2) < kvalid ? p[2] : 0.f;
            v.w = (k + 3) < kvalid ? p[3] : 0.f;
        }
        s[row][f4 * 4 + 0] = v.x; s[row][f4 * 4 + 1] = v.y;
        s[row][f4 * 4 + 2] = v.z; s[row][f4 * 4 + 3] = v.w;
    }
    __syncthreads();

    const size_t base = ((size_t)mt * nktiles + kt) * 4096;
#pragma unroll
    for (int it = 0; it < 2; ++it) {
        int o   = it * 256 + tid;          // 512 chunks of 8 ushorts
        int kb  = o >> 7;
        int row = o & 127;
        alignas(16) ushort_t hbuf[8];
        alignas(16) ushort_t lbuf[8];
#pragma unroll
        for (int e = 0; e < 8; ++e) {
            float x = s[row][kb * 8 + e];
            ushort_t hh = f2bf_rn(x);
            float lof = x - bf2f(hh);
            hbuf[e] = hh;
            lbuf[e] = f2bf_rn(lof);
        }
        *(uint4*)(hi + base + (size_t)o * 8) = *(const uint4*)hbuf;
        *(uint4*)(lo + base + (size_t)o * 8) = *(const uint4*)lbuf;
    }
}

// ---------------------------------------------------------------------------
// px_mfma: PX[m,n] = b_in[n] + sum_k X[m,k]*Win[n,k] via 3-term split bf16.
// Epilogue writes TRANSPOSED: PXT[t][n][b]  (t = row>>8, b = row&255).
// ---------------------------------------------------------------------------
__device__ inline void gload16(const ushort_t* g, ushort_t* l) {
    __builtin_amdgcn_global_load_lds(
        (const __attribute__((address_space(1))) void*)g,
        (__attribute__((address_space(3))) void*)l, 16, 0, 0);
}

__global__ __launch_bounds__(256) void px_mfma(
    const ushort_t* __restrict__ Ah, const ushort_t* __restrict__ Al,
    const ushort_t* __restrict__ Bh, const ushort_t* __restrict__ Bl,
    const float* __restrict__ b_in, float* __restrict__ PXT)
{
    __shared__ ushort_t sAh[4096], sAl[4096], sBh[4096], sBl[4096]; // 32 KiB

    const int tid  = threadIdx.x;
    const int wave = tid >> 6;
    const int lane = tid & 63;
    const int mt = blockIdx.y, ntb = blockIdx.x;
    const int wr = wave >> 1, wc = wave & 1;

    f32x4 acc[4][4];
#pragma unroll
    for (int i = 0; i < 4; ++i)
#pragma unroll
        for (int j = 0; j < 4; ++j) acc[i][j] = (f32x4){0.f, 0.f, 0.f, 0.f};

    const size_t abase = (size_t)mt * NKT * 4096;
    const size_t bbase = (size_t)ntb * NKT * 4096;
    const int lw = wave * 512;
    const int kb = lane >> 4;
    const int lr = lane & 15;
    const int aoff = kb * 1024 + (wr * 64 + lr) * 8;
    const int boff = kb * 1024 + (wc * 64 + lr) * 8;

    for (int kt = 0; kt < NKT; ++kt) {
        const size_t ko = (size_t)kt * 4096 + tid * 8;
        gload16(Ah + abase + ko,        &sAh[lw]);
        gload16(Ah + abase + ko + 2048, &sAh[2048 + lw]);
        gload16(Al + abase + ko,        &sAl[lw]);
        gload16(Al + abase + ko + 2048, &sAl[2048 + lw]);
        gload16(Bh + bbase + ko,        &sBh[lw]);
        gload16(Bh + bbase + ko + 2048, &sBh[2048 + lw]);
        gload16(Bl + bbase + ko,        &sBl[lw]);
        gload16(Bl + bbase + ko + 2048, &sBl[2048 + lw]);
        __syncthreads();

        short8 ah[4], al[4], bh[4], bl[4];
#pragma unroll
        for (int i = 0; i < 4; ++i) {
            ah[i] = *(const short8*)&sAh[aoff + i * 128];
            al[i] = *(const short8*)&sAl[aoff + i * 128];
        }
#pragma unroll
        for (int j = 0; j < 4; ++j) {
            bh[j] = *(const short8*)&sBh[boff + j * 128];
            bl[j] = *(const short8*)&sBl[boff + j * 128];
        }
#pragma unroll
        for (int i = 0; i < 4; ++i)
#pragma unroll
            for (int j = 0; j < 4; ++j) {
                acc[i][j] = __builtin_amdgcn_mfma_f32_16x16x32_bf16(ah[i], bh[j], acc[i][j], 0, 0, 0);
                acc[i][j] = __builtin_amdgcn_mfma_f32_16x16x32_bf16(ah[i], bl[j], acc[i][j], 0, 0, 0);
                acc[i][j] = __builtin_amdgcn_mfma_f32_16x16x32_bf16(al[i], bh[j], acc[i][j], 0, 0, 0);
            }
        __syncthreads();
    }

#pragma unroll
    for (int i = 0; i < 4; ++i) {
        const int row = mt * 128 + wr * 64 + i * 16 + (lane >> 4) * 4;
        const int tl  = row >> 8;
        const int bb  = row & 255;
#pragma unroll
        for (int j = 0; j < 4; ++j) {
            const int col = ntb * 128 + wc * 64 + j * 16 + (lane & 15);
            const float bias = b_in[col];
            float4 v = {acc[i][j][0] + bias, acc[i][j][1] + bias,
                        acc[i][j][2] + bias, acc[i][j][3] + bias};
            *(float4*)(PXT + (size_t)tl * (SIXH * 256) + (size_t)col * 256 + bb) = v;
        }
    }
}

// ---------------------------------------------------------------------------
// ew_gemm: EW[m,n] = sum_k embed[m,k] * Win[n, 4936+k]   (m<152, K=200)
// ---------------------------------------------------------------------------
__global__ __launch_bounds__(256) void ew_gemm(
    const float* __restrict__ embed, const float* __restrict__ Win,
    float* __restrict__ EW)
{
    __shared__ float As[16][68];
    __shared__ float Bs[16][68];
    const int tid = threadIdx.x;
    const int tx  = tid & 15;
    const int ty  = tid >> 4;
    const int n0  = blockIdx.x * 64;
    const int m0  = blockIdx.y * 64;
    const int lrow = tid >> 2;
    const int lk   = (tid & 3) * 4;

    float acc[4][4];
#pragma unroll
    for (int i = 0; i < 4; ++i)
#pragma unroll
        for (int j = 0; j < 4; ++j) acc[i][j] = 0.f;

    for (int k0 = 0; k0 < EMB; k0 += 16) {
        int k = k0 + lk;
        float4 av = {0.f,0.f,0.f,0.f}, bv = {0.f,0.f,0.f,0.f};
        if (k < EMB) {
            int am = m0 + lrow;
            if (am < 152) av = *(const float4*)(embed + (size_t)am * EMB + k);
            bv = *(const float4*)(Win + (size_t)(n0 + lrow) * DE + DIM + k);
        }
        __syncthreads();
        As[lk + 0][lrow] = av.x; As[lk + 1][lrow] = av.y;
        As[lk + 2][lrow] = av.z; As[lk + 3][lrow] = av.w;
        Bs[lk + 0][lrow] = bv.x; Bs[lk + 1][lrow] = bv.y;
        Bs[lk + 2][lrow] = bv.z; Bs[lk + 3][lrow] = bv.w;
        __syncthreads();
#pragma unroll
        for (int kk = 0; kk < 16; ++kk) {
            float4 a4 = *(const float4*)&As[kk][ty * 4];
            float4 b4 = *(const float4*)&Bs[kk][tx * 4];
            float avr[4] = {a4.x, a4.y, a4.z, a4.w};
            float bvr[4] = {b4.x, b4.y, b4.z, b4.w};
#pragma unroll
            for (int i = 0; i < 4; ++i)
#pragma unroll
                for (int j = 0; j < 4; ++j)
                    acc[i][j] = fmaf(avr[i], bvr[j], acc[i][j]);
        }
    }
#pragma unroll
    for (int i = 0; i < 4; ++i) {
        int m = m0 + ty * 4 + i;
        if (m < 152) {
#pragma unroll
            for (int j = 0; j < 4; ++j)
                EW[(size_t)m * SIXH + n0 + tx * 4 + j] = acc[i][j];
        }
    }
}

__global__ void zero_bar(unsigned* p) { *p = 0u; }

// ---------------------------------------------------------------------------
// recurrence: persistent kernel, 256 blocks x 512 threads, whole step chain.
// Phase A: block (btile 4 x uslab 64): ps dot (Wst from LDS) + gates; c in regs.
// Phase B: block = batch row: pred = h@Wout.T + argmax -> commit.
// Grid barrier: monotone counter + device-scope atomics.
// ---------------------------------------------------------------------------
__global__ __launch_bounds__(512, 2) void recurrence(
    const float* __restrict__ Wst, const float* __restrict__ b_state,
    const float* __restrict__ Wout, const float* __restrict__ b_out,
    const float* __restrict__ EW, const float* __restrict__ pxT,
    float* __restrict__ h2, float* __restrict__ cT,
    float* __restrict__ dists, int* __restrict__ commits,
    unsigned* __restrict__ bar, int t0, int nt)
{
    __shared__ float wst_l[8][5][512];   // 80 KiB, persistent across steps
    __shared__ float hsh[512];
    __shared__ float parts[304];
    __shared__ float preds[NCLS + 1];

    const int tid  = threadIdx.x;
    const int bx   = blockIdx.x;          // 0..255
    const int btile = bx >> 6;            // 0..3
    const int u0    = (bx & 63) * 8;
    const int wv    = tid >> 6;           // 0..7  (uniform per wave)
    const int lane  = tid & 63;
    const int b     = btile * 64 + lane;  // phase-A batch row
    const int u     = u0 + wv;            // phase-A hidden unit

    // stage Wst slab: [uu][k2][512]
    for (int i = tid; i < 8 * 5 * 128; i += 512) {
        int uu = i / 640; int r = i - uu * 640;
        int k2 = r >> 7;  int kf = r & 127;
        float4 v = *(const float4*)(Wst + (size_t)(k2 * 512 + u0 + uu) * 512 + kf * 4);
        *(float4*)&wst_l[uu][k2][kf * 4] = v;
    }
    float bst[5];
#pragma unroll
    for (int k2 = 0; k2 < 5; ++k2) bst[k2] = b_state[k2 * 512 + u];
    __syncthreads();

    float c_reg = (t0 == 0) ? 0.f : cT[(size_t)u * 256 + b];
    unsigned target = 0;

    for (int t = t0; t < t0 + nt; ++t) {
        // ---------------- phase A ----------------
        float s[5];
        if (t > 0) {
            const float* hb = h2 + (((t - 1) & 1) ? 131072 : 0) + (size_t)b * 512;
            f32x4 sv[5];
#pragma unroll
            for (int k2 = 0; k2 < 5; ++k2) sv[k2] = (f32x4){0.f, 0.f, 0.f, 0.f};
#pragma unroll 4
            for (int k0 = 0; k0 < 512; k0 += 4) {
                float4 hv = *(const float4*)(hb + k0);
#pragma unroll
                for (int k2 = 0; k2 < 5; ++k2) {
                    float4 w4 = *(const float4*)&wst_l[wv][k2][k0];
                    sv[k2][0] = fmaf(hv.x, w4.x, sv[k2][0]);
                    sv[k2][1] = fmaf(hv.y, w4.y, sv[k2][1]);
                    sv[k2][2] = fmaf(hv.z, w4.z, sv[k2][2]);
                    sv[k2][3] = fmaf(hv.w, w4.w, sv[k2][3]);
                }
            }
#pragma unroll
            for (int k2 = 0; k2 < 5; ++k2)
                s[k2] = (sv[k2][0] + sv[k2][1]) + (sv[k2][2] + sv[k2][3]);
        } else {
#pragma unroll
            for (int k2 = 0; k2 < 5; ++k2) s[k2] = 0.f;
        }

        const int cm = (t == 0) ? 0 : (commits[(t - 1) * 256 + b] + 1);
        const float* ew  = EW + (size_t)cm * SIXH;
        const float* pxb = pxT + (size_t)(t - t0) * (SIXH * 256) + b;
        float p[6];
#pragma unroll
        for (int k2 = 0; k2 < 6; ++k2)
            p[k2] = pxb[(size_t)(k2 * 512 + u) * 256] + ew[k2 * 512 + u];
#pragma unroll
        for (int k2 = 0; k2 < 5; ++k2) p[k2] += s[k2] + bst[k2];

        float i_g = sigmoidf(p[0]);
        float f_g = sigmoidf(p[1]);
        float m_i = tanhf(p[2]);
        float o_g = sigmoidf(p[3]);
        c_reg = i_g * m_i + f_g * c_reg;
        float outv = o_g * tanhf(c_reg);
        float hw   = sigmoidf(p[4]);
        float h_new = hw * outv + (1.f - hw) * p[5];
        float* hcur = h2 + ((t & 1) ? 131072 : 0);
        hcur[(size_t)b * 512 + u] = h_new;

        // ---- grid barrier 1 ----
        __syncthreads();
        if (tid == 0) {
            __threadfence();
            atomicAdd(bar, 1u);
            target += 256;
            while (__hip_atomic_load(bar, __ATOMIC_ACQUIRE, __HIP_MEMORY_SCOPE_AGENT) < target)
                __builtin_amdgcn_s_sleep(1);
        }
        __syncthreads();

        // ---------------- phase B ----------------
        const int bb = bx;
        if (tid < 128) {
            float4 v = *(const float4*)(hcur + (size_t)bb * 512 + tid * 4);
            *(float4*)&hsh[tid * 4] = v;
        }
        __syncthreads();
        if (tid < 302) {
            const int cls = tid >> 1, hf = tid & 1;
            const float* w  = Wout + (size_t)cls * 512 + hf * 256;
            const float* hh = &hsh[hf * 256];
            float a0 = 0.f, a1 = 0.f, a2 = 0.f, a3 = 0.f;
#pragma unroll 4
            for (int k = 0; k < 256; k += 4) {
                float4 w4 = *(const float4*)(w + k);
                float4 h4 = *(const float4*)(hh + k);
                a0 = fmaf(h4.x, w4.x, a0);
                a1 = fmaf(h4.y, w4.y, a1);
                a2 = fmaf(h4.z, w4.z, a2);
                a3 = fmaf(h4.w, w4.w, a3);
            }
            parts[tid] = (a0 + a1) + (a2 + a3);
        }
        __syncthreads();
        if (tid < NCLS) {
            float pr = b_out[tid] + parts[2 * tid] + parts[2 * tid + 1];
            preds[tid] = pr;
            dists[((size_t)t * 256 + bb) * NCLS + tid] = pr;
        }
        __syncthreads();
        if (tid == 0) {
            int bi = 1; float bv = preds[1];
            for (int n = 2; n < NCLS; ++n) {
                float v = preds[n];
                if (v > bv) { bv = v; bi = n; }
            }
            commits[t * 256 + bb] = bi;
        }

        // ---- grid barrier 2 ----
        __syncthreads();
        if (tid == 0) {
            __threadfence();
            atomicAdd(bar, 1u);
            target += 256;
            while (__hip_atomic_load(bar, __ATOMIC_ACQUIRE, __HIP_MEMORY_SCOPE_AGENT) < target)
                __builtin_amdgcn_s_sleep(1);
        }
        __syncthreads();
    }

    cT[(size_t)u * 256 + b] = c_reg;
}

// ---------------------------------------------------------------------------
__global__ __launch_bounds__(192) void gather_out(
    const float* __restrict__ dists, const int* __restrict__ commits,
    const int* __restrict__ gidx, float* __restrict__ out)
{
    const int i = blockIdx.x;
    const int g = gidx[i];
    if (threadIdx.x < NCLS)
        out[(size_t)i * NCLS + threadIdx.x] = dists[(size_t)g * NCLS + threadIdx.x];
    if (threadIdx.x == NCLS)
        out[(size_t)NPACK * NCLS + i] = (float)commits[g];
}

// ---------------------------------------------------------------------------
extern "C" void kernel_launch(void* const* d_in, const int* in_sizes, int n_in,
                              void* d_out, int out_size, void* d_ws, size_t ws_size,
                              hipStream_t stream)
{
    const float* X      = (const float*)d_in[0];  // [80,256,4936]
    const float* embed  = (const float*)d_in[1];  // [152,200]
    const float* Win    = (const float*)d_in[2];  // [3072,5136]
    const float* b_in   = (const float*)d_in[3];
    const float* Wst    = (const float*)d_in[4];  // [2560,512]
    const float* b_st   = (const float*)d_in[5];
    const float* Wout   = (const float*)d_in[6];  // [151,512]
    const float* b_out  = (const float*)d_in[7];
    const int*   gidx   = (const int*)d_in[8];

    const size_t WN = (size_t)24 * NKT * 4096;    // ushorts per W array
    ushort_t* Wh = (ushort_t*)d_ws;
    ushort_t* Wl = Wh + WN;
    float* EW    = (float*)(Wl + WN);
    float* h2    = EW + (size_t)152 * SIXH;        // 2 x 256 x 512
    float* cT    = h2 + 2 * 131072;                // 512 x 256
    float* dists = cT + 131072;
    int* commits = (int*)(dists + (size_t)T_STEPS * BATCH * NCLS);
    unsigned* bar = (unsigned*)(commits + T_STEPS * BATCH);
    char* cbase  = (char*)(bar + 64);

    size_t off = (size_t)(cbase - (char*)d_ws);
    off = (off + 255) & ~(size_t)255;
    const size_t per_t = (size_t)2 * 2 * NKT * 4096 * 2 + (size_t)BATCH * SIXH * 4;
    size_t rem = (ws_size > off) ? (ws_size - off) : 0;
    int CT = (int)(rem / per_t);
    if (CT > T_STEPS) CT = T_STEPS;
    if (CT < 1) CT = 1;

    ushort_t* Xh = (ushort_t*)((char*)d_ws + off);
    ushort_t* Xl = Xh + (size_t)2 * CT * NKT * 4096;
    float* pxT   = (float*)(Xl + (size_t)2 * CT * NKT * 4096);

    // one-time prep
    convert_split<<<dim3(NKT, 24), 256, 0, stream>>>(Win, DE, DIM, Wh, Wl, NKT);
    ew_gemm<<<dim3(SIXH / 64, 3), 256, 0, stream>>>(embed, Win, EW);

    for (int t0 = 0; t0 < T_STEPS; t0 += CT) {
        int nt = T_STEPS - t0;
        if (nt > CT) nt = CT;
        convert_split<<<dim3(NKT, 2 * nt), 256, 0, stream>>>(
            X + (size_t)t0 * BATCH * DIM, DIM, DIM, Xh, Xl, NKT);
        px_mfma<<<dim3(SIXH / 128, 2 * nt), 256, 0, stream>>>(
            Xh, Xl, Wh, Wl, b_in, pxT);
        zero_bar<<<1, 1, 0, stream>>>(bar);
        recurrence<<<256, 512, 0, stream>>>(
            Wst, b_st, Wout, b_out, EW, pxT, h2, cT, dists, commits, bar, t0, nt);
    }

    gather_out<<<NPACK, 192, 0, stream>>>(dists, commits, gidx, (float*)d_out);
}

// Round 4
// 5334.193 us; speedup vs baseline: 1.8618x; 1.8618x over previous
//
#include <hip/hip_runtime.h>
#include <cstddef>
#include <cstdint>

#define T_STEPS 80
#define BATCH   256
#define DIM     4936
#define EMB     200
#define DE      5136
#define HID     512
#define SIXH    3072
#define FIVEH   2560
#define NCLS    151
#define NPACK   15504
#define NKT     156          // ceil(4936/32) for px; Kpad = 4992
#define NKT_H   16           // 512/32 for ps

typedef unsigned short ushort_t;
typedef short short8 __attribute__((ext_vector_type(8)));
typedef float f32x4 __attribute__((ext_vector_type(4)));

__device__ inline ushort_t f2bf_rn(float x) {
    union { float f; uint32_t u; } v; v.f = x;
    uint32_t u = v.u;
    return (ushort_t)((u + 0x7FFFu + ((u >> 16) & 1u)) >> 16);
}
__device__ inline float bf2f(ushort_t b) {
    union { float f; uint32_t u; } v; v.u = ((uint32_t)b) << 16;
    return v.f;
}
__device__ inline float sigmoidf(float x) { return 1.f / (1.f + expf(-x)); }

// ---------------------------------------------------------------------------
// convert_split: src [ntiles*128 rows, ld] fp32 -> hi/lo bf16 in tiled layout
// out[mtile][ktile][kb(4)][row(128)][8]   (zero-padded for k >= kvalid)
// ---------------------------------------------------------------------------
__global__ __launch_bounds__(256) void convert_split(
    const float* __restrict__ src, int ld, int kvalid,
    ushort_t* __restrict__ hi, ushort_t* __restrict__ lo, int nktiles)
{
    __shared__ float s[128][33];
    const int tid = threadIdx.x;
    const int kt  = blockIdx.x;
    const int mt  = blockIdx.y;

#pragma unroll
    for (int it = 0; it < 4; ++it) {
        int idx = it * 256 + tid;          // 1024 float4 slots
        int row = idx >> 3;
        int f4  = idx & 7;
        int k   = kt * 32 + f4 * 4;
        const float* p = src + (size_t)(mt * 128 + row) * ld + k;
        float4 v;
        if (k + 3 < kvalid) v = *(const float4*)p;
        else {
            v.x = (k + 0) < kvalid ? p[0] : 0.f;
            v.y = (k + 1) < kvalid ? p[1] : 0.f;
            v.z = (k + 2) < kvalid ? p[2] : 0.f;
            v.w = (k + 3) < kvalid ? p[3] : 0.f;
        }
        s[row][f4 * 4 + 0] = v.x; s[row][f4 * 4 + 1] = v.y;
        s[row][f4 * 4 + 2] = v.z; s[row][f4 * 4 + 3] = v.w;
    }
    __syncthreads();

    const size_t base = ((size_t)mt * nktiles + kt) * 4096;
#pragma unroll
    for (int it = 0; it < 2; ++it) {
        int o   = it * 256 + tid;          // 512 chunks of 8 ushorts
        int kb  = o >> 7;
        int row = o & 127;
        alignas(16) ushort_t hbuf[8];
        alignas(16) ushort_t lbuf[8];
#pragma unroll
        for (int e = 0; e < 8; ++e) {
            float x = s[row][kb * 8 + e];
            ushort_t hh = f2bf_rn(x);
            float lof = x - bf2f(hh);
            hbuf[e] = hh;
            lbuf[e] = f2bf_rn(lof);
        }
        *(uint4*)(hi + base + (size_t)o * 8) = *(const uint4*)hbuf;
        *(uint4*)(lo + base + (size_t)o * 8) = *(const uint4*)lbuf;
    }
}

// ---------------------------------------------------------------------------
// mfma3: OUT[m,n] = bias[n] + sum_k A[m,k]*B[n,k] via 3-term split bf16.
// 128x128 tile, BK=32, 4 waves, each wave 64x64 (4x4 frags of 16x16x32).
// A/B pre-tiled [mt][kt][kb][row][8]; staged with global_load_lds (16B).
// Used for px (nkt=156, ld=3072) and ps (nkt=16, ld=2560).
// ---------------------------------------------------------------------------
__device__ inline void gload16(const ushort_t* g, ushort_t* l) {
    __builtin_amdgcn_global_load_lds(
        (const __attribute__((address_space(1))) void*)g,
        (__attribute__((address_space(3))) void*)l, 16, 0, 0);
}

__global__ __launch_bounds__(256) void mfma3(
    const ushort_t* __restrict__ Ah, const ushort_t* __restrict__ Al,
    const ushort_t* __restrict__ Bh, const ushort_t* __restrict__ Bl,
    const float* __restrict__ bias, float* __restrict__ OUT,
    int nkt, int ldout)
{
    __shared__ ushort_t sAh[4096], sAl[4096], sBh[4096], sBl[4096]; // 32 KiB

    const int tid  = threadIdx.x;
    const int wave = tid >> 6;
    const int lane = tid & 63;
    const int mt = blockIdx.y, ntb = blockIdx.x;
    const int wr = wave >> 1, wc = wave & 1;

    f32x4 acc[4][4];
#pragma unroll
    for (int i = 0; i < 4; ++i)
#pragma unroll
        for (int j = 0; j < 4; ++j) acc[i][j] = (f32x4){0.f, 0.f, 0.f, 0.f};

    const size_t abase = (size_t)mt * nkt * 4096;
    const size_t bbase = (size_t)ntb * nkt * 4096;
    const int lw = wave * 512;
    const int kb = lane >> 4;
    const int lr = lane & 15;
    const int aoff = kb * 1024 + (wr * 64 + lr) * 8;
    const int boff = kb * 1024 + (wc * 64 + lr) * 8;

    for (int kt = 0; kt < nkt; ++kt) {
        const size_t ko = (size_t)kt * 4096 + tid * 8;
        gload16(Ah + abase + ko,        &sAh[lw]);
        gload16(Ah + abase + ko + 2048, &sAh[2048 + lw]);
        gload16(Al + abase + ko,        &sAl[lw]);
        gload16(Al + abase + ko + 2048, &sAl[2048 + lw]);
        gload16(Bh + bbase + ko,        &sBh[lw]);
        gload16(Bh + bbase + ko + 2048, &sBh[2048 + lw]);
        gload16(Bl + bbase + ko,        &sBl[lw]);
        gload16(Bl + bbase + ko + 2048, &sBl[2048 + lw]);
        __syncthreads();

        short8 ah[4], al[4], bh[4], bl[4];
#pragma unroll
        for (int i = 0; i < 4; ++i) {
            ah[i] = *(const short8*)&sAh[aoff + i * 128];
            al[i] = *(const short8*)&sAl[aoff + i * 128];
        }
#pragma unroll
        for (int j = 0; j < 4; ++j) {
            bh[j] = *(const short8*)&sBh[boff + j * 128];
            bl[j] = *(const short8*)&sBl[boff + j * 128];
        }
#pragma unroll
        for (int i = 0; i < 4; ++i)
#pragma unroll
            for (int j = 0; j < 4; ++j) {
                acc[i][j] = __builtin_amdgcn_mfma_f32_16x16x32_bf16(ah[i], bh[j], acc[i][j], 0, 0, 0);
                acc[i][j] = __builtin_amdgcn_mfma_f32_16x16x32_bf16(ah[i], bl[j], acc[i][j], 0, 0, 0);
                acc[i][j] = __builtin_amdgcn_mfma_f32_16x16x32_bf16(al[i], bh[j], acc[i][j], 0, 0, 0);
            }
        __syncthreads();
    }

#pragma unroll
    for (int i = 0; i < 4; ++i) {
        const int row = mt * 128 + wr * 64 + i * 16 + (lane >> 4) * 4;
#pragma unroll
        for (int j = 0; j < 4; ++j) {
            const int col = ntb * 128 + wc * 64 + j * 16 + (lane & 15);
            const float bv = bias[col];
#pragma unroll
            for (int r = 0; r < 4; ++r)
                OUT[(size_t)(row + r) * ldout + col] = acc[i][j][r] + bv;
        }
    }
}

// ---------------------------------------------------------------------------
// ew_gemm: EW[m,n] = sum_k embed[m,k] * Win[n, 4936+k]   (m<152, K=200)
// ---------------------------------------------------------------------------
__global__ __launch_bounds__(256) void ew_gemm(
    const float* __restrict__ embed, const float* __restrict__ Win,
    float* __restrict__ EW)
{
    __shared__ float As[16][68];
    __shared__ float Bs[16][68];
    const int tid = threadIdx.x;
    const int tx  = tid & 15;
    const int ty  = tid >> 4;
    const int n0  = blockIdx.x * 64;
    const int m0  = blockIdx.y * 64;
    const int lrow = tid >> 2;
    const int lk   = (tid & 3) * 4;

    float acc[4][4];
#pragma unroll
    for (int i = 0; i < 4; ++i)
#pragma unroll
        for (int j = 0; j < 4; ++j) acc[i][j] = 0.f;

    for (int k0 = 0; k0 < EMB; k0 += 16) {
        int k = k0 + lk;
        float4 av = {0.f,0.f,0.f,0.f}, bv = {0.f,0.f,0.f,0.f};
        if (k < EMB) {
            int am = m0 + lrow;
            if (am < 152) av = *(const float4*)(embed + (size_t)am * EMB + k);
            bv = *(const float4*)(Win + (size_t)(n0 + lrow) * DE + DIM + k);
        }
        __syncthreads();
        As[lk + 0][lrow] = av.x; As[lk + 1][lrow] = av.y;
        As[lk + 2][lrow] = av.z; As[lk + 3][lrow] = av.w;
        Bs[lk + 0][lrow] = bv.x; Bs[lk + 1][lrow] = bv.y;
        Bs[lk + 2][lrow] = bv.z; Bs[lk + 3][lrow] = bv.w;
        __syncthreads();
#pragma unroll
        for (int kk = 0; kk < 16; ++kk) {
            float4 a4 = *(const float4*)&As[kk][ty * 4];
            float4 b4 = *(const float4*)&Bs[kk][tx * 4];
            float avr[4] = {a4.x, a4.y, a4.z, a4.w};
            float bvr[4] = {b4.x, b4.y, b4.z, b4.w};
#pragma unroll
            for (int i = 0; i < 4; ++i)
#pragma unroll
                for (int j = 0; j < 4; ++j)
                    acc[i][j] = fmaf(avr[i], bvr[j], acc[i][j]);
        }
    }
#pragma unroll
    for (int i = 0; i < 4; ++i) {
        int m = m0 + ty * 4 + i;
        if (m < 152) {
#pragma unroll
            for (int j = 0; j < 4; ++j)
                EW[(size_t)m * SIXH + n0 + tx * 4 + j] = acc[i][j];
        }
    }
}

// ---------------------------------------------------------------------------
// step_update: gates -> h,c; pred = h@Wout.T + b_out; argmax -> commit.
// Also emits h as hi/lo bf16 in MFMA tile layout for next step's ps GEMM.
// ---------------------------------------------------------------------------
__global__ __launch_bounds__(256) void step_update(
    const float* __restrict__ px_t,        // [256, 3072]
    const float* __restrict__ EW,          // [152, 3072]
    const float* __restrict__ ps,          // [256, 2560]
    const int*   __restrict__ commit_prev, // [256] (prev step)
    int first,
    const float* __restrict__ Wout, const float* __restrict__ b_out,
    ushort_t* __restrict__ hHt, ushort_t* __restrict__ hLt,  // tiled h
    float* __restrict__ c,
    float* __restrict__ dists_t, int* __restrict__ commit_t)
{
    __shared__ float hs[HID];
    __shared__ float preds[NCLS];

    const int b   = blockIdx.x;
    const int tid = threadIdx.x;
    const int erow = first ? 0 : (commit_prev[b] + 1);
    const float* ew  = EW + (size_t)erow * SIXH;
    const float* px  = px_t + (size_t)b * SIXH;
    const float* psr = ps + (size_t)b * FIVEH;

    for (int u = tid; u < HID; u += 256) {
        float p0 = px[u]           + ew[u]           + psr[u];
        float p1 = px[HID + u]     + ew[HID + u]     + psr[HID + u];
        float p2 = px[2*HID + u]   + ew[2*HID + u]   + psr[2*HID + u];
        float p3 = px[3*HID + u]   + ew[3*HID + u]   + psr[3*HID + u];
        float p4 = px[4*HID + u]   + ew[4*HID + u]   + psr[4*HID + u];
        float p5 = px[5*HID + u]   + ew[5*HID + u];
        float i_g = sigmoidf(p0);
        float f_g = sigmoidf(p1);
        float m_i = tanhf(p2);
        float o_g = sigmoidf(p3);
        float c_new = i_g * m_i + f_g * c[(size_t)b * HID + u];
        float outv  = o_g * tanhf(c_new);
        float hw    = sigmoidf(p4);
        float h_new = hw * outv + (1.f - hw) * p5;
        c[(size_t)b * HID + u] = c_new;
        hs[u] = h_new;
    }
    __syncthreads();

    // emit tiled bf16 h (hi: tid<64, lo: 64<=tid<128); chunk = 8 k-values
    if (tid < 128) {
        const int cchunk = tid & 63;
        const int mt  = b >> 7;
        const int row = b & 127;
        const size_t off = ((size_t)(mt * NKT_H + (cchunk >> 2))) * 4096
                         + (size_t)(cchunk & 3) * 1024 + (size_t)row * 8;
        alignas(16) ushort_t buf[8];
        if (tid < 64) {
#pragma unroll
            for (int e = 0; e < 8; ++e) buf[e] = f2bf_rn(hs[cchunk * 8 + e]);
            *(uint4*)(hHt + off) = *(const uint4*)buf;
        } else {
#pragma unroll
            for (int e = 0; e < 8; ++e) {
                float x = hs[cchunk * 8 + e];
                buf[e] = f2bf_rn(x - bf2f(f2bf_rn(x)));
            }
            *(uint4*)(hLt + off) = *(const uint4*)buf;
        }
    }

    if (tid < NCLS) {
        const float* w = Wout + (size_t)tid * HID;
        float s0 = 0.f, s1 = 0.f, s2 = 0.f, s3 = 0.f;
        for (int k = 0; k < HID; k += 4) {
            s0 = fmaf(hs[k + 0], w[k + 0], s0);
            s1 = fmaf(hs[k + 1], w[k + 1], s1);
            s2 = fmaf(hs[k + 2], w[k + 2], s2);
            s3 = fmaf(hs[k + 3], w[k + 3], s3);
        }
        float s = b_out[tid] + ((s0 + s1) + (s2 + s3));
        preds[tid] = s;
        dists_t[(size_t)b * NCLS + tid] = s;
    }
    __syncthreads();

    if (tid == 0) {
        int   bi = 1;
        float bv = preds[1];
        for (int n = 2; n < NCLS; ++n) {
            float v = preds[n];
            if (v > bv) { bv = v; bi = n; }
        }
        commit_t[b] = bi;
    }
}

// ---------------------------------------------------------------------------
__global__ __launch_bounds__(192) void gather_out(
    const float* __restrict__ dists, const int* __restrict__ commits,
    const int* __restrict__ gidx, float* __restrict__ out)
{
    const int i = blockIdx.x;
    const int g = gidx[i];
    if (threadIdx.x < NCLS)
        out[(size_t)i * NCLS + threadIdx.x] = dists[(size_t)g * NCLS + threadIdx.x];
    if (threadIdx.x == NCLS)
        out[(size_t)NPACK * NCLS + i] = (float)commits[g];
}

// init: c = 0, tiled h hi/lo = 0 (so first ps == b_state)
__global__ __launch_bounds__(256) void init_state(
    float* __restrict__ c, ushort_t* __restrict__ hHt, ushort_t* __restrict__ hLt)
{
    int i = blockIdx.x * 256 + threadIdx.x;
    if (i < BATCH * HID) { c[i] = 0.f; hHt[i] = 0; hLt[i] = 0; }
}

// ---------------------------------------------------------------------------
extern "C" void kernel_launch(void* const* d_in, const int* in_sizes, int n_in,
                              void* d_out, int out_size, void* d_ws, size_t ws_size,
                              hipStream_t stream)
{
    const float* X      = (const float*)d_in[0];  // [80,256,4936]
    const float* embed  = (const float*)d_in[1];  // [152,200]
    const float* Win    = (const float*)d_in[2];  // [3072,5136]
    const float* b_in   = (const float*)d_in[3];
    const float* Wst    = (const float*)d_in[4];  // [2560,512]
    const float* b_st   = (const float*)d_in[5];
    const float* Wout   = (const float*)d_in[6];  // [151,512]
    const float* b_out  = (const float*)d_in[7];
    const int*   gidx   = (const int*)d_in[8];

    const size_t WN  = (size_t)24 * NKT * 4096;    // ushorts per Win-split array
    const size_t WSN = (size_t)20 * NKT_H * 4096;  // ushorts per Wst-split array
    const size_t HN  = (size_t)2 * NKT_H * 4096;   // ushorts per h-split array

    ushort_t* Wh   = (ushort_t*)d_ws;
    ushort_t* Wl   = Wh + WN;
    ushort_t* WstH = Wl + WN;
    ushort_t* WstL = WstH + WSN;
    ushort_t* hHt  = WstL + WSN;
    ushort_t* hLt  = hHt + HN;
    float* EW    = (float*)(hLt + HN);
    float* ps    = EW + (size_t)152 * SIXH;
    float* c     = ps + (size_t)BATCH * FIVEH;
    float* dists = c + (size_t)BATCH * HID;
    int* commits = (int*)(dists + (size_t)T_STEPS * BATCH * NCLS);
    char* cbase  = (char*)(commits + T_STEPS * BATCH);

    size_t off = (size_t)(cbase - (char*)d_ws);
    off = (off + 255) & ~(size_t)255;
    const size_t per_t = (size_t)2 * 2 * NKT * 4096 * 2 + (size_t)BATCH * SIXH * 4;
    size_t rem = (ws_size > off) ? (ws_size - off) : 0;
    int CT = (int)(rem / per_t);
    if (CT > T_STEPS) CT = T_STEPS;
    if (CT < 1) CT = 1;

    ushort_t* Xh = (ushort_t*)((char*)d_ws + off);
    ushort_t* Xl = Xh + (size_t)2 * CT * NKT * 4096;
    float* px    = (float*)(Xl + (size_t)2 * CT * NKT * 4096);

    // one-time prep
    convert_split<<<dim3(NKT, 24), 256, 0, stream>>>(Win, DE, DIM, Wh, Wl, NKT);
    convert_split<<<dim3(NKT_H, 20), 256, 0, stream>>>(Wst, HID, HID, WstH, WstL, NKT_H);
    ew_gemm<<<dim3(SIXH / 64, 3), 256, 0, stream>>>(embed, Win, EW);
    init_state<<<512, 256, 0, stream>>>(c, hHt, hLt);

    for (int t0 = 0; t0 < T_STEPS; t0 += CT) {
        int nt = T_STEPS - t0;
        if (nt > CT) nt = CT;
        convert_split<<<dim3(NKT, 2 * nt), 256, 0, stream>>>(
            X + (size_t)t0 * BATCH * DIM, DIM, DIM, Xh, Xl, NKT);
        mfma3<<<dim3(SIXH / 128, 2 * nt), 256, 0, stream>>>(
            Xh, Xl, Wh, Wl, b_in, px, NKT, SIXH);
        for (int t = t0; t < t0 + nt; ++t) {
            mfma3<<<dim3(FIVEH / 128, BATCH / 128), 256, 0, stream>>>(
                hHt, hLt, WstH, WstL, b_st, ps, NKT_H, FIVEH);
            step_update<<<BATCH, 256, 0, stream>>>(
                px + (size_t)(t - t0) * BATCH * SIXH, EW, ps,
                commits + (size_t)(t > 0 ? t - 1 : 0) * BATCH, (t == 0) ? 1 : 0,
                Wout, b_out, hHt, hLt, c,
                dists + (size_t)t * BATCH * NCLS, commits + (size_t)t * BATCH);
        }
    }

    gather_out<<<NPACK, 192, 0, stream>>>(dists, commits, gidx, (float*)d_out);
}

// Round 5
// 4603.676 us; speedup vs baseline: 2.1572x; 1.1587x over previous
//
#include <hip/hip_runtime.h>
#include <cstddef>
#include <cstdint>

#define T_STEPS 80
#define BATCH   256
#define DIM     4936
#define EMB     200
#define DE      5136
#define HID     512
#define SIXH    3072
#define FIVEH   2560
#define NCLS    151
#define NPACK   15504
#define NKT     156          // ceil(4936/32) for px; Kpad = 4992
#define NKT_H   16           // 512/32 for ps

typedef unsigned short ushort_t;
typedef short short8 __attribute__((ext_vector_type(8)));
typedef float f32x4 __attribute__((ext_vector_type(4)));

__device__ inline ushort_t f2bf_rn(float x) {
    union { float f; uint32_t u; } v; v.f = x;
    uint32_t u = v.u;
    return (ushort_t)((u + 0x7FFFu + ((u >> 16) & 1u)) >> 16);
}
__device__ inline float bf2f(ushort_t b) {
    union { float f; uint32_t u; } v; v.u = ((uint32_t)b) << 16;
    return v.f;
}
__device__ inline float sigmoidf(float x) { return 1.f / (1.f + expf(-x)); }

// ---------------------------------------------------------------------------
// convert_split: src [ntiles*128 rows, ld] fp32 -> hi/lo bf16 in tiled layout
// out[mtile][ktile][kb(4)][row(128)][8]   (zero-padded for k >= kvalid)
// ---------------------------------------------------------------------------
__global__ __launch_bounds__(256) void convert_split(
    const float* __restrict__ src, int ld, int kvalid,
    ushort_t* __restrict__ hi, ushort_t* __restrict__ lo, int nktiles)
{
    __shared__ float s[128][33];
    const int tid = threadIdx.x;
    const int kt  = blockIdx.x;
    const int mt  = blockIdx.y;

#pragma unroll
    for (int it = 0; it < 4; ++it) {
        int idx = it * 256 + tid;          // 1024 float4 slots
        int row = idx >> 3;
        int f4  = idx & 7;
        int k   = kt * 32 + f4 * 4;
        const float* p = src + (size_t)(mt * 128 + row) * ld + k;
        float4 v;
        if (k + 3 < kvalid) v = *(const float4*)p;
        else {
            v.x = (k + 0) < kvalid ? p[0] : 0.f;
            v.y = (k + 1) < kvalid ? p[1] : 0.f;
            v.z = (k + 2) < kvalid ? p[2] : 0.f;
            v.w = (k + 3) < kvalid ? p[3] : 0.f;
        }
        s[row][f4 * 4 + 0] = v.x; s[row][f4 * 4 + 1] = v.y;
        s[row][f4 * 4 + 2] = v.z; s[row][f4 * 4 + 3] = v.w;
    }
    __syncthreads();

    const size_t base = ((size_t)mt * nktiles + kt) * 4096;
#pragma unroll
    for (int it = 0; it < 2; ++it) {
        int o   = it * 256 + tid;          // 512 chunks of 8 ushorts
        int kb  = o >> 7;
        int row = o & 127;
        alignas(16) ushort_t hbuf[8];
        alignas(16) ushort_t lbuf[8];
#pragma unroll
        for (int e = 0; e < 8; ++e) {
            float x = s[row][kb * 8 + e];
            ushort_t hh = f2bf_rn(x);
            float lof = x - bf2f(hh);
            hbuf[e] = hh;
            lbuf[e] = f2bf_rn(lof);
        }
        *(uint4*)(hi + base + (size_t)o * 8) = *(const uint4*)hbuf;
        *(uint4*)(lo + base + (size_t)o * 8) = *(const uint4*)lbuf;
    }
}

// ---------------------------------------------------------------------------
__device__ inline void gload16(const ushort_t* g, ushort_t* l) {
    __builtin_amdgcn_global_load_lds(
        (const __attribute__((address_space(1))) void*)g,
        (__attribute__((address_space(3))) void*)l, 16, 0, 0);
}

// ---------------------------------------------------------------------------
// mfma3: OUT[m,n] = bias[n] + sum_k A[m,k]*B[n,k] via 3-term split bf16.
// 128x128 tile, BK=32, 4 waves. Used for the big px GEMM only.
// ---------------------------------------------------------------------------
__global__ __launch_bounds__(256) void mfma3(
    const ushort_t* __restrict__ Ah, const ushort_t* __restrict__ Al,
    const ushort_t* __restrict__ Bh, const ushort_t* __restrict__ Bl,
    const float* __restrict__ bias, float* __restrict__ OUT,
    int nkt, int ldout)
{
    __shared__ ushort_t sAh[4096], sAl[4096], sBh[4096], sBl[4096]; // 32 KiB

    const int tid  = threadIdx.x;
    const int wave = tid >> 6;
    const int lane = tid & 63;
    const int mt = blockIdx.y, ntb = blockIdx.x;
    const int wr = wave >> 1, wc = wave & 1;

    f32x4 acc[4][4];
#pragma unroll
    for (int i = 0; i < 4; ++i)
#pragma unroll
        for (int j = 0; j < 4; ++j) acc[i][j] = (f32x4){0.f, 0.f, 0.f, 0.f};

    const size_t abase = (size_t)mt * nkt * 4096;
    const size_t bbase = (size_t)ntb * nkt * 4096;
    const int lw = wave * 512;
    const int kb = lane >> 4;
    const int lr = lane & 15;
    const int aoff = kb * 1024 + (wr * 64 + lr) * 8;
    const int boff = kb * 1024 + (wc * 64 + lr) * 8;

    for (int kt = 0; kt < nkt; ++kt) {
        const size_t ko = (size_t)kt * 4096 + tid * 8;
        gload16(Ah + abase + ko,        &sAh[lw]);
        gload16(Ah + abase + ko + 2048, &sAh[2048 + lw]);
        gload16(Al + abase + ko,        &sAl[lw]);
        gload16(Al + abase + ko + 2048, &sAl[2048 + lw]);
        gload16(Bh + bbase + ko,        &sBh[lw]);
        gload16(Bh + bbase + ko + 2048, &sBh[2048 + lw]);
        gload16(Bl + bbase + ko,        &sBl[lw]);
        gload16(Bl + bbase + ko + 2048, &sBl[2048 + lw]);
        __syncthreads();

        short8 ah[4], al[4], bh[4], bl[4];
#pragma unroll
        for (int i = 0; i < 4; ++i) {
            ah[i] = *(const short8*)&sAh[aoff + i * 128];
            al[i] = *(const short8*)&sAl[aoff + i * 128];
        }
#pragma unroll
        for (int j = 0; j < 4; ++j) {
            bh[j] = *(const short8*)&sBh[boff + j * 128];
            bl[j] = *(const short8*)&sBl[boff + j * 128];
        }
#pragma unroll
        for (int i = 0; i < 4; ++i)
#pragma unroll
            for (int j = 0; j < 4; ++j) {
                acc[i][j] = __builtin_amdgcn_mfma_f32_16x16x32_bf16(ah[i], bh[j], acc[i][j], 0, 0, 0);
                acc[i][j] = __builtin_amdgcn_mfma_f32_16x16x32_bf16(ah[i], bl[j], acc[i][j], 0, 0, 0);
                acc[i][j] = __builtin_amdgcn_mfma_f32_16x16x32_bf16(al[i], bh[j], acc[i][j], 0, 0, 0);
            }
        __syncthreads();
    }

#pragma unroll
    for (int i = 0; i < 4; ++i) {
        const int row = mt * 128 + wr * 64 + i * 16 + (lane >> 4) * 4;
#pragma unroll
        for (int j = 0; j < 4; ++j) {
            const int col = ntb * 128 + wc * 64 + j * 16 + (lane & 15);
            const float bv = bias[col];
#pragma unroll
            for (int r = 0; r < 4; ++r)
                OUT[(size_t)(row + r) * ldout + col] = acc[i][j][r] + bv;
        }
    }
}

// ---------------------------------------------------------------------------
// ps_splitk: partial[ks][m,n] = sum_{k in slice ks} h[m,k]*Wst[n,k]
// 64x64 tile, K-split 4 (128 K each = 4 BK32 iters). 640 blocks -> TLP.
// ---------------------------------------------------------------------------
__global__ __launch_bounds__(256) void ps_splitk(
    const ushort_t* __restrict__ hH, const ushort_t* __restrict__ hL,
    const ushort_t* __restrict__ WsH, const ushort_t* __restrict__ WsL,
    float* __restrict__ partial)   // [4][256][2560]
{
    __shared__ ushort_t sAh[2048], sAl[2048], sBh[2048], sBl[2048]; // 16 KiB

    const int tid  = threadIdx.x;
    const int wave = tid >> 6;
    const int lane = tid & 63;
    const int ntile = blockIdx.x;   // 0..39
    const int mtile = blockIdx.y;   // 0..3
    const int ks    = blockIdx.z;   // 0..3
    const int amt = mtile >> 1, arh = mtile & 1;
    const int bmt = ntile >> 1, brh = ntile & 1;
    const int wr = wave >> 1, wc = wave & 1;

    f32x4 acc[2][2];
#pragma unroll
    for (int i = 0; i < 2; ++i)
#pragma unroll
        for (int j = 0; j < 2; ++j) acc[i][j] = (f32x4){0.f, 0.f, 0.f, 0.f};

    const int lw   = wave * 512;
    const int lsrcA = (tid >> 6) * 1024 + arh * 512 + (tid & 63) * 8;
    const int lsrcB = (tid >> 6) * 1024 + brh * 512 + (tid & 63) * 8;
    const int kb = lane >> 4;
    const int lr = lane & 15;

#pragma unroll
    for (int ki = 0; ki < 4; ++ki) {
        const int kt = ks * 4 + ki;
        const size_t atile = ((size_t)(amt * NKT_H + kt)) * 4096;
        const size_t btile = ((size_t)(bmt * NKT_H + kt)) * 4096;
        gload16(hH  + atile + lsrcA, &sAh[lw]);
        gload16(hL  + atile + lsrcA, &sAl[lw]);
        gload16(WsH + btile + lsrcB, &sBh[lw]);
        gload16(WsL + btile + lsrcB, &sBl[lw]);
        __syncthreads();

        short8 ah[2], al[2], bh[2], bl[2];
#pragma unroll
        for (int i = 0; i < 2; ++i) {
            const int ao = kb * 512 + (wr * 32 + i * 16 + lr) * 8;
            ah[i] = *(const short8*)&sAh[ao];
            al[i] = *(const short8*)&sAl[ao];
        }
#pragma unroll
        for (int j = 0; j < 2; ++j) {
            const int bo = kb * 512 + (wc * 32 + j * 16 + lr) * 8;
            bh[j] = *(const short8*)&sBh[bo];
            bl[j] = *(const short8*)&sBl[bo];
        }
#pragma unroll
        for (int i = 0; i < 2; ++i)
#pragma unroll
            for (int j = 0; j < 2; ++j) {
                acc[i][j] = __builtin_amdgcn_mfma_f32_16x16x32_bf16(ah[i], bh[j], acc[i][j], 0, 0, 0);
                acc[i][j] = __builtin_amdgcn_mfma_f32_16x16x32_bf16(ah[i], bl[j], acc[i][j], 0, 0, 0);
                acc[i][j] = __builtin_amdgcn_mfma_f32_16x16x32_bf16(al[i], bh[j], acc[i][j], 0, 0, 0);
            }
        __syncthreads();
    }

    float* out = partial + ((size_t)ks * 256 + mtile * 64) * FIVEH + ntile * 64;
#pragma unroll
    for (int i = 0; i < 2; ++i) {
        const int row = wr * 32 + i * 16 + (lane >> 4) * 4;
#pragma unroll
        for (int j = 0; j < 2; ++j) {
            const int col = wc * 32 + j * 16 + (lane & 15);
#pragma unroll
            for (int r = 0; r < 4; ++r)
                out[(size_t)(row + r) * FIVEH + col] = acc[i][j][r];
        }
    }
}

// ---------------------------------------------------------------------------
// ew_gemm: EW[m,n] = sum_k embed[m,k] * Win[n, 4936+k]   (m<152, K=200)
// ---------------------------------------------------------------------------
__global__ __launch_bounds__(256) void ew_gemm(
    const float* __restrict__ embed, const float* __restrict__ Win,
    float* __restrict__ EW)
{
    __shared__ float As[16][68];
    __shared__ float Bs[16][68];
    const int tid = threadIdx.x;
    const int tx  = tid & 15;
    const int ty  = tid >> 4;
    const int n0  = blockIdx.x * 64;
    const int m0  = blockIdx.y * 64;
    const int lrow = tid >> 2;
    const int lk   = (tid & 3) * 4;

    float acc[4][4];
#pragma unroll
    for (int i = 0; i < 4; ++i)
#pragma unroll
        for (int j = 0; j < 4; ++j) acc[i][j] = 0.f;

    for (int k0 = 0; k0 < EMB; k0 += 16) {
        int k = k0 + lk;
        float4 av = {0.f,0.f,0.f,0.f}, bv = {0.f,0.f,0.f,0.f};
        if (k < EMB) {
            int am = m0 + lrow;
            if (am < 152) av = *(const float4*)(embed + (size_t)am * EMB + k);
            bv = *(const float4*)(Win + (size_t)(n0 + lrow) * DE + DIM + k);
        }
        __syncthreads();
        As[lk + 0][lrow] = av.x; As[lk + 1][lrow] = av.y;
        As[lk + 2][lrow] = av.z; As[lk + 3][lrow] = av.w;
        Bs[lk + 0][lrow] = bv.x; Bs[lk + 1][lrow] = bv.y;
        Bs[lk + 2][lrow] = bv.z; Bs[lk + 3][lrow] = bv.w;
        __syncthreads();
#pragma unroll
        for (int kk = 0; kk < 16; ++kk) {
            float4 a4 = *(const float4*)&As[kk][ty * 4];
            float4 b4 = *(const float4*)&Bs[kk][tx * 4];
            float avr[4] = {a4.x, a4.y, a4.z, a4.w};
            float bvr[4] = {b4.x, b4.y, b4.z, b4.w};
#pragma unroll
            for (int i = 0; i < 4; ++i)
#pragma unroll
                for (int j = 0; j < 4; ++j)
                    acc[i][j] = fmaf(avr[i], bvr[j], acc[i][j]);
        }
    }
#pragma unroll
    for (int i = 0; i < 4; ++i) {
        int m = m0 + ty * 4 + i;
        if (m < 152) {
#pragma unroll
            for (int j = 0; j < 4; ++j)
                EW[(size_t)m * SIXH + n0 + tx * 4 + j] = acc[i][j];
        }
    }
}

// ---------------------------------------------------------------------------
// step_fused: 128 blocks x 2 batch rows. Sums partials + bias, gates,
// c/h update, tiled bf16 h emit, pred (Wout read once per block), argmax.
// ---------------------------------------------------------------------------
__global__ __launch_bounds__(256) void step_fused(
    const float* __restrict__ px_t,        // [256, 3072]
    const float* __restrict__ EW,          // [152, 3072]
    const float* __restrict__ partial,     // [4][256][2560]
    const float* __restrict__ b_state,     // [2560]
    const int*   __restrict__ commit_prev, // [256]
    int first,
    const float* __restrict__ Wout, const float* __restrict__ b_out,
    ushort_t* __restrict__ hHt, ushort_t* __restrict__ hLt,
    float* __restrict__ c,
    float* __restrict__ dists_t, int* __restrict__ commit_t)
{
    __shared__ float hs[2][HID];
    __shared__ float preds[2][NCLS + 1];

    const int tid = threadIdx.x;
    const int bx  = blockIdx.x;

#pragma unroll
    for (int it = 0; it < 4; ++it) {
        const int idx = it * 256 + tid;
        const int r = idx >> 9, u = idx & 511;
        const int b = bx * 2 + r;
        const int erow = first ? 0 : (commit_prev[b] + 1);
        const float* ew = EW + (size_t)erow * SIXH;
        const float* px = px_t + (size_t)b * SIXH;
        const float* pp = partial + (size_t)b * FIVEH;
        float p[6];
#pragma unroll
        for (int k2 = 0; k2 < 5; ++k2) {
            const int o = k2 * HID + u;
            float s = pp[o] + pp[256 * FIVEH + o]
                    + pp[2 * 256 * FIVEH + o] + pp[3 * 256 * FIVEH + o];
            p[k2] = px[o] + ew[o] + s + b_state[o];
        }
        p[5] = px[5 * HID + u] + ew[5 * HID + u];

        float i_g = sigmoidf(p[0]);
        float f_g = sigmoidf(p[1]);
        float m_i = tanhf(p[2]);
        float o_g = sigmoidf(p[3]);
        float c_new = i_g * m_i + f_g * c[(size_t)b * HID + u];
        float outv  = o_g * tanhf(c_new);
        float hw    = sigmoidf(p[4]);
        float h_new = hw * outv + (1.f - hw) * p[5];
        c[(size_t)b * HID + u] = c_new;
        hs[r][u] = h_new;
    }
    __syncthreads();

    // tiled bf16 h emit: tid -> (row r, hi/lo half, 8-elem chunk)
    {
        const int r    = tid >> 7;
        const int half = (tid >> 6) & 1;
        const int ch   = tid & 63;
        const int b    = bx * 2 + r;
        const int mt   = b >> 7;
        const int row  = b & 127;
        const size_t off = ((size_t)(mt * NKT_H + (ch >> 2))) * 4096
                         + (size_t)(ch & 3) * 1024 + (size_t)row * 8;
        alignas(16) ushort_t buf[8];
        if (half == 0) {
#pragma unroll
            for (int e = 0; e < 8; ++e) buf[e] = f2bf_rn(hs[r][ch * 8 + e]);
            *(uint4*)(hHt + off) = *(const uint4*)buf;
        } else {
#pragma unroll
            for (int e = 0; e < 8; ++e) {
                float x = hs[r][ch * 8 + e];
                buf[e] = f2bf_rn(x - bf2f(f2bf_rn(x)));
            }
            *(uint4*)(hLt + off) = *(const uint4*)buf;
        }
    }

    if (tid < NCLS) {
        const float* w = Wout + (size_t)tid * HID;
        float s00 = 0.f, s01 = 0.f, s02 = 0.f, s03 = 0.f;
        float s10 = 0.f, s11 = 0.f, s12 = 0.f, s13 = 0.f;
        for (int k = 0; k < HID; k += 4) {
            float4 w4 = *(const float4*)(w + k);
            float4 h0 = *(const float4*)&hs[0][k];
            float4 h1 = *(const float4*)&hs[1][k];
            s00 = fmaf(h0.x, w4.x, s00); s01 = fmaf(h0.y, w4.y, s01);
            s02 = fmaf(h0.z, w4.z, s02); s03 = fmaf(h0.w, w4.w, s03);
            s10 = fmaf(h1.x, w4.x, s10); s11 = fmaf(h1.y, w4.y, s11);
            s12 = fmaf(h1.z, w4.z, s12); s13 = fmaf(h1.w, w4.w, s13);
        }
        const float bo = b_out[tid];
        float p0 = bo + ((s00 + s01) + (s02 + s03));
        float p1 = bo + ((s10 + s11) + (s12 + s13));
        preds[0][tid] = p0;
        preds[1][tid] = p1;
        dists_t[(size_t)(bx * 2 + 0) * NCLS + tid] = p0;
        dists_t[(size_t)(bx * 2 + 1) * NCLS + tid] = p1;
    }
    __syncthreads();

    if (tid < 2) {
        int   bi = 1;
        float bv = preds[tid][1];
        for (int n = 2; n < NCLS; ++n) {
            float v = preds[tid][n];
            if (v > bv) { bv = v; bi = n; }
        }
        commit_t[bx * 2 + tid] = bi;
    }
}

// ---------------------------------------------------------------------------
__global__ __launch_bounds__(192) void gather_out(
    const float* __restrict__ dists, const int* __restrict__ commits,
    const int* __restrict__ gidx, float* __restrict__ out)
{
    const int i = blockIdx.x;
    const int g = gidx[i];
    if (threadIdx.x < NCLS)
        out[(size_t)i * NCLS + threadIdx.x] = dists[(size_t)g * NCLS + threadIdx.x];
    if (threadIdx.x == NCLS)
        out[(size_t)NPACK * NCLS + i] = (float)commits[g];
}

// init: c = 0, tiled h hi/lo = 0 (so first ps partials == 0)
__global__ __launch_bounds__(256) void init_state(
    float* __restrict__ c, ushort_t* __restrict__ hHt, ushort_t* __restrict__ hLt)
{
    int i = blockIdx.x * 256 + threadIdx.x;
    if (i < BATCH * HID) { c[i] = 0.f; hHt[i] = 0; hLt[i] = 0; }
}

// ---------------------------------------------------------------------------
extern "C" void kernel_launch(void* const* d_in, const int* in_sizes, int n_in,
                              void* d_out, int out_size, void* d_ws, size_t ws_size,
                              hipStream_t stream)
{
    const float* X      = (const float*)d_in[0];  // [80,256,4936]
    const float* embed  = (const float*)d_in[1];  // [152,200]
    const float* Win    = (const float*)d_in[2];  // [3072,5136]
    const float* b_in   = (const float*)d_in[3];
    const float* Wst    = (const float*)d_in[4];  // [2560,512]
    const float* b_st   = (const float*)d_in[5];
    const float* Wout   = (const float*)d_in[6];  // [151,512]
    const float* b_out  = (const float*)d_in[7];
    const int*   gidx   = (const int*)d_in[8];

    const size_t WN  = (size_t)24 * NKT * 4096;    // ushorts per Win-split array
    const size_t WSN = (size_t)20 * NKT_H * 4096;  // ushorts per Wst-split array
    const size_t HN  = (size_t)2 * NKT_H * 4096;   // ushorts per h-split array

    ushort_t* Wh   = (ushort_t*)d_ws;
    ushort_t* Wl   = Wh + WN;
    ushort_t* WstH = Wl + WN;
    ushort_t* WstL = WstH + WSN;
    ushort_t* hHt  = WstL + WSN;
    ushort_t* hLt  = hHt + HN;
    float* EW      = (float*)(hLt + HN);
    float* partial = EW + (size_t)152 * SIXH;            // 4*256*2560
    float* c       = partial + (size_t)4 * BATCH * FIVEH;
    float* dists   = c + (size_t)BATCH * HID;
    int* commits   = (int*)(dists + (size_t)T_STEPS * BATCH * NCLS);
    char* cbase    = (char*)(commits + T_STEPS * BATCH);

    size_t off = (size_t)(cbase - (char*)d_ws);
    off = (off + 255) & ~(size_t)255;
    const size_t per_t = (size_t)2 * 2 * NKT * 4096 * 2 + (size_t)BATCH * SIXH * 4;
    size_t rem = (ws_size > off) ? (ws_size - off) : 0;
    int CT = (int)(rem / per_t);
    if (CT > T_STEPS) CT = T_STEPS;
    if (CT < 1) CT = 1;

    ushort_t* Xh = (ushort_t*)((char*)d_ws + off);
    ushort_t* Xl = Xh + (size_t)2 * CT * NKT * 4096;
    float* px    = (float*)(Xl + (size_t)2 * CT * NKT * 4096);

    // one-time prep
    convert_split<<<dim3(NKT, 24), 256, 0, stream>>>(Win, DE, DIM, Wh, Wl, NKT);
    convert_split<<<dim3(NKT_H, 20), 256, 0, stream>>>(Wst, HID, HID, WstH, WstL, NKT_H);
    ew_gemm<<<dim3(SIXH / 64, 3), 256, 0, stream>>>(embed, Win, EW);
    init_state<<<512, 256, 0, stream>>>(c, hHt, hLt);

    for (int t0 = 0; t0 < T_STEPS; t0 += CT) {
        int nt = T_STEPS - t0;
        if (nt > CT) nt = CT;
        convert_split<<<dim3(NKT, 2 * nt), 256, 0, stream>>>(
            X + (size_t)t0 * BATCH * DIM, DIM, DIM, Xh, Xl, NKT);
        mfma3<<<dim3(SIXH / 128, 2 * nt), 256, 0, stream>>>(
            Xh, Xl, Wh, Wl, b_in, px, NKT, SIXH);
        for (int t = t0; t < t0 + nt; ++t) {
            ps_splitk<<<dim3(40, 4, 4), 256, 0, stream>>>(
                hHt, hLt, WstH, WstL, partial);
            step_fused<<<128, 256, 0, stream>>>(
                px + (size_t)(t - t0) * BATCH * SIXH, EW, partial, b_st,
                commits + (size_t)(t > 0 ? t - 1 : 0) * BATCH, (t == 0) ? 1 : 0,
                Wout, b_out, hHt, hLt, c,
                dists + (size_t)t * BATCH * NCLS, commits + (size_t)t * BATCH);
        }
    }

    gather_out<<<NPACK, 192, 0, stream>>>(dists, commits, gidx, (float*)d_out);
}

// Round 6
// 4403.370 us; speedup vs baseline: 2.2553x; 1.0455x over previous
//
#include <hip/hip_runtime.h>
#include <cstddef>
#include <cstdint>

#define T_STEPS 80
#define BATCH   256
#define DIM     4936
#define EMB     200
#define DE      5136
#define HID     512
#define SIXH    3072
#define FIVEH   2560
#define NCLS    151
#define NPACK   15504
#define NKT     156          // ceil(4936/32) for px; Kpad = 4992
#define NKT_H   16           // 512/32 for ps

typedef unsigned short ushort_t;
typedef short short8 __attribute__((ext_vector_type(8)));
typedef float f32x4 __attribute__((ext_vector_type(4)));

__device__ inline ushort_t f2bf_rn(float x) {
    union { float f; uint32_t u; } v; v.f = x;
    uint32_t u = v.u;
    return (ushort_t)((u + 0x7FFFu + ((u >> 16) & 1u)) >> 16);
}
__device__ inline float bf2f(ushort_t b) {
    union { float f; uint32_t u; } v; v.u = ((uint32_t)b) << 16;
    return v.f;
}
__device__ inline float sigmoidf(float x) { return 1.f / (1.f + expf(-x)); }

// ---------------------------------------------------------------------------
// convert_split: src [ntiles*128 rows, ld] fp32 -> hi/lo bf16 in tiled layout
// out[mtile][ktile][kb(4)][row(128)][8]   (zero-padded for k >= kvalid)
// ---------------------------------------------------------------------------
__global__ __launch_bounds__(256) void convert_split(
    const float* __restrict__ src, int ld, int kvalid,
    ushort_t* __restrict__ hi, ushort_t* __restrict__ lo, int nktiles)
{
    __shared__ float s[128][33];
    const int tid = threadIdx.x;
    const int kt  = blockIdx.x;
    const int mt  = blockIdx.y;

#pragma unroll
    for (int it = 0; it < 4; ++it) {
        int idx = it * 256 + tid;          // 1024 float4 slots
        int row = idx >> 3;
        int f4  = idx & 7;
        int k   = kt * 32 + f4 * 4;
        const float* p = src + (size_t)(mt * 128 + row) * ld + k;
        float4 v;
        if (k + 3 < kvalid) v = *(const float4*)p;
        else {
            v.x = (k + 0) < kvalid ? p[0] : 0.f;
            v.y = (k + 1) < kvalid ? p[1] : 0.f;
            v.z = (k + 2) < kvalid ? p[2] : 0.f;
            v.w = (k + 3) < kvalid ? p[3] : 0.f;
        }
        s[row][f4 * 4 + 0] = v.x; s[row][f4 * 4 + 1] = v.y;
        s[row][f4 * 4 + 2] = v.z; s[row][f4 * 4 + 3] = v.w;
    }
    __syncthreads();

    const size_t base = ((size_t)mt * nktiles + kt) * 4096;
#pragma unroll
    for (int it = 0; it < 2; ++it) {
        int o   = it * 256 + tid;          // 512 chunks of 8 ushorts
        int kb  = o >> 7;
        int row = o & 127;
        alignas(16) ushort_t hbuf[8];
        alignas(16) ushort_t lbuf[8];
#pragma unroll
        for (int e = 0; e < 8; ++e) {
            float x = s[row][kb * 8 + e];
            ushort_t hh = f2bf_rn(x);
            float lof = x - bf2f(hh);
            hbuf[e] = hh;
            lbuf[e] = f2bf_rn(lof);
        }
        *(uint4*)(hi + base + (size_t)o * 8) = *(const uint4*)hbuf;
        *(uint4*)(lo + base + (size_t)o * 8) = *(const uint4*)lbuf;
    }
}

// ---------------------------------------------------------------------------
__device__ inline void gload16(const ushort_t* g, ushort_t* l) {
    __builtin_amdgcn_global_load_lds(
        (const __attribute__((address_space(1))) void*)g,
        (__attribute__((address_space(3))) void*)l, 16, 0, 0);
}

// ---------------------------------------------------------------------------
// mfma3: OUT[m,n] = bias[n] + sum_k A[m,k]*B[n,k] via 3-term split bf16.
// 128x128 tile, BK=32, 4 waves. 2-phase double-buffered LDS (prefetch kt+1
// while computing kt; raw s_barrier + asm vmcnt so prefetch isn't drained).
// 1D grid with bijective XCD swizzle (nwg % 8 == 0 always: nwg = 48*nt).
// ---------------------------------------------------------------------------
__global__ __launch_bounds__(256) void mfma3(
    const ushort_t* __restrict__ Ah, const ushort_t* __restrict__ Al,
    const ushort_t* __restrict__ Bh, const ushort_t* __restrict__ Bl,
    const float* __restrict__ bias, float* __restrict__ OUT,
    int nkt, int ldout, int ntx, int nwg)
{
    __shared__ ushort_t sAh[2][4096], sAl[2][4096], sBh[2][4096], sBl[2][4096];

    const int tid  = threadIdx.x;
    const int wave = tid >> 6;
    const int lane = tid & 63;

    // XCD swizzle: blocks with consecutive compute-ids land on the same XCD
    int L = blockIdx.x;
    int swz = L;
    if ((nwg & 7) == 0) swz = (L & 7) * (nwg >> 3) + (L >> 3);
    const int mt  = swz / ntx;
    const int ntb = swz - mt * ntx;
    const int wr = wave >> 1, wc = wave & 1;

    f32x4 acc[4][4];
#pragma unroll
    for (int i = 0; i < 4; ++i)
#pragma unroll
        for (int j = 0; j < 4; ++j) acc[i][j] = (f32x4){0.f, 0.f, 0.f, 0.f};

    const size_t abase = (size_t)mt * nkt * 4096;
    const size_t bbase = (size_t)ntb * nkt * 4096;
    const int lw = wave * 512;
    const int kb = lane >> 4;
    const int lr = lane & 15;
    const int aoff = kb * 1024 + (wr * 64 + lr) * 8;
    const int boff = kb * 1024 + (wc * 64 + lr) * 8;

#define STAGE_PX(buf, kt_) do {                                     \
        const size_t ko = (size_t)(kt_) * 4096 + tid * 8;           \
        gload16(Ah + abase + ko,        &sAh[buf][lw]);             \
        gload16(Ah + abase + ko + 2048, &sAh[buf][2048 + lw]);      \
        gload16(Al + abase + ko,        &sAl[buf][lw]);             \
        gload16(Al + abase + ko + 2048, &sAl[buf][2048 + lw]);      \
        gload16(Bh + bbase + ko,        &sBh[buf][lw]);             \
        gload16(Bh + bbase + ko + 2048, &sBh[buf][2048 + lw]);      \
        gload16(Bl + bbase + ko,        &sBl[buf][lw]);             \
        gload16(Bl + bbase + ko + 2048, &sBl[buf][2048 + lw]);      \
    } while (0)

    // prologue: stage tile 0, wait, barrier
    STAGE_PX(0, 0);
    asm volatile("s_waitcnt vmcnt(0)" ::: "memory");
    __builtin_amdgcn_s_barrier();

    int cur = 0;
    for (int kt = 0; kt < nkt; ++kt) {
        if (kt + 1 < nkt) STAGE_PX(cur ^ 1, kt + 1);   // prefetch next tile

        const ushort_t* pAh = sAh[cur];
        const ushort_t* pAl = sAl[cur];
        const ushort_t* pBh = sBh[cur];
        const ushort_t* pBl = sBl[cur];
        short8 ah[4], al[4], bh[4], bl[4];
#pragma unroll
        for (int i = 0; i < 4; ++i) {
            ah[i] = *(const short8*)&pAh[aoff + i * 128];
            al[i] = *(const short8*)&pAl[aoff + i * 128];
        }
#pragma unroll
        for (int j = 0; j < 4; ++j) {
            bh[j] = *(const short8*)&pBh[boff + j * 128];
            bl[j] = *(const short8*)&pBl[boff + j * 128];
        }
#pragma unroll
        for (int i = 0; i < 4; ++i)
#pragma unroll
            for (int j = 0; j < 4; ++j) {
                acc[i][j] = __builtin_amdgcn_mfma_f32_16x16x32_bf16(ah[i], bh[j], acc[i][j], 0, 0, 0);
                acc[i][j] = __builtin_amdgcn_mfma_f32_16x16x32_bf16(ah[i], bl[j], acc[i][j], 0, 0, 0);
                acc[i][j] = __builtin_amdgcn_mfma_f32_16x16x32_bf16(al[i], bh[j], acc[i][j], 0, 0, 0);
            }

        __builtin_amdgcn_sched_barrier(0);
        asm volatile("s_waitcnt vmcnt(0)" ::: "memory");   // next tile staged
        __builtin_amdgcn_s_barrier();                      // all waves done reading
        cur ^= 1;
    }
#undef STAGE_PX

#pragma unroll
    for (int i = 0; i < 4; ++i) {
        const int row = mt * 128 + wr * 64 + i * 16 + (lane >> 4) * 4;
#pragma unroll
        for (int j = 0; j < 4; ++j) {
            const int col = ntb * 128 + wc * 64 + j * 16 + (lane & 15);
            const float bv = bias[col];
#pragma unroll
            for (int r = 0; r < 4; ++r)
                OUT[(size_t)(row + r) * ldout + col] = acc[i][j][r] + bv;
        }
    }
}

// ---------------------------------------------------------------------------
// ps_splitk: partial[ks][m,n] = sum_{k in slice ks} h[m,k]*Wst[n,k]
// 64x64 tile, K-split 4. All 4 K-iters staged at once (64 KB LDS), ONE
// barrier, then 48 straight MFMAs. 640 blocks -> TLP.
// ---------------------------------------------------------------------------
__global__ __launch_bounds__(256) void ps_splitk(
    const ushort_t* __restrict__ hH, const ushort_t* __restrict__ hL,
    const ushort_t* __restrict__ WsH, const ushort_t* __restrict__ WsL,
    float* __restrict__ partial)   // [4][256][2560]
{
    __shared__ ushort_t sAh[8192], sAl[8192], sBh[8192], sBl[8192]; // 64 KiB

    const int tid  = threadIdx.x;
    const int wave = tid >> 6;
    const int lane = tid & 63;
    const int ntile = blockIdx.x;   // 0..39
    const int mtile = blockIdx.y;   // 0..3
    const int ks    = blockIdx.z;   // 0..3
    const int amt = mtile >> 1, arh = mtile & 1;
    const int bmt = ntile >> 1, brh = ntile & 1;
    const int wr = wave >> 1, wc = wave & 1;

    f32x4 acc[2][2];
#pragma unroll
    for (int i = 0; i < 2; ++i)
#pragma unroll
        for (int j = 0; j < 2; ++j) acc[i][j] = (f32x4){0.f, 0.f, 0.f, 0.f};

    const int lw    = wave * 512;
    const int lsrcA = wave * 1024 + arh * 512 + lane * 8;
    const int lsrcB = wave * 1024 + brh * 512 + lane * 8;

#pragma unroll
    for (int ki = 0; ki < 4; ++ki) {
        const int kt = ks * 4 + ki;
        const size_t atile = ((size_t)(amt * NKT_H + kt)) * 4096;
        const size_t btile = ((size_t)(bmt * NKT_H + kt)) * 4096;
        gload16(hH  + atile + lsrcA, &sAh[ki * 2048 + lw]);
        gload16(hL  + atile + lsrcA, &sAl[ki * 2048 + lw]);
        gload16(WsH + btile + lsrcB, &sBh[ki * 2048 + lw]);
        gload16(WsL + btile + lsrcB, &sBl[ki * 2048 + lw]);
    }
    __syncthreads();   // single drain: all 16 stages visible

    const int kb = lane >> 4;
    const int lr = lane & 15;
#pragma unroll
    for (int ki = 0; ki < 4; ++ki) {
        short8 ah[2], al[2], bh[2], bl[2];
#pragma unroll
        for (int i = 0; i < 2; ++i) {
            const int ao = ki * 2048 + kb * 512 + (wr * 32 + i * 16 + lr) * 8;
            ah[i] = *(const short8*)&sAh[ao];
            al[i] = *(const short8*)&sAl[ao];
        }
#pragma unroll
        for (int j = 0; j < 2; ++j) {
            const int bo = ki * 2048 + kb * 512 + (wc * 32 + j * 16 + lr) * 8;
            bh[j] = *(const short8*)&sBh[bo];
            bl[j] = *(const short8*)&sBl[bo];
        }
#pragma unroll
        for (int i = 0; i < 2; ++i)
#pragma unroll
            for (int j = 0; j < 2; ++j) {
                acc[i][j] = __builtin_amdgcn_mfma_f32_16x16x32_bf16(ah[i], bh[j], acc[i][j], 0, 0, 0);
                acc[i][j] = __builtin_amdgcn_mfma_f32_16x16x32_bf16(ah[i], bl[j], acc[i][j], 0, 0, 0);
                acc[i][j] = __builtin_amdgcn_mfma_f32_16x16x32_bf16(al[i], bh[j], acc[i][j], 0, 0, 0);
            }
    }

    float* out = partial + ((size_t)ks * 256 + mtile * 64) * FIVEH + ntile * 64;
#pragma unroll
    for (int i = 0; i < 2; ++i) {
        const int row = wr * 32 + i * 16 + (lane >> 4) * 4;
#pragma unroll
        for (int j = 0; j < 2; ++j) {
            const int col = wc * 32 + j * 16 + (lane & 15);
#pragma unroll
            for (int r = 0; r < 4; ++r)
                out[(size_t)(row + r) * FIVEH + col] = acc[i][j][r];
        }
    }
}

// ---------------------------------------------------------------------------
// ew_gemm: EW[m,n] = sum_k embed[m,k] * Win[n, 4936+k]   (m<152, K=200)
// ---------------------------------------------------------------------------
__global__ __launch_bounds__(256) void ew_gemm(
    const float* __restrict__ embed, const float* __restrict__ Win,
    float* __restrict__ EW)
{
    __shared__ float As[16][68];
    __shared__ float Bs[16][68];
    const int tid = threadIdx.x;
    const int tx  = tid & 15;
    const int ty  = tid >> 4;
    const int n0  = blockIdx.x * 64;
    const int m0  = blockIdx.y * 64;
    const int lrow = tid >> 2;
    const int lk   = (tid & 3) * 4;

    float acc[4][4];
#pragma unroll
    for (int i = 0; i < 4; ++i)
#pragma unroll
        for (int j = 0; j < 4; ++j) acc[i][j] = 0.f;

    for (int k0 = 0; k0 < EMB; k0 += 16) {
        int k = k0 + lk;
        float4 av = {0.f,0.f,0.f,0.f}, bv = {0.f,0.f,0.f,0.f};
        if (k < EMB) {
            int am = m0 + lrow;
            if (am < 152) av = *(const float4*)(embed + (size_t)am * EMB + k);
            bv = *(const float4*)(Win + (size_t)(n0 + lrow) * DE + DIM + k);
        }
        __syncthreads();
        As[lk + 0][lrow] = av.x; As[lk + 1][lrow] = av.y;
        As[lk + 2][lrow] = av.z; As[lk + 3][lrow] = av.w;
        Bs[lk + 0][lrow] = bv.x; Bs[lk + 1][lrow] = bv.y;
        Bs[lk + 2][lrow] = bv.z; Bs[lk + 3][lrow] = bv.w;
        __syncthreads();
#pragma unroll
        for (int kk = 0; kk < 16; ++kk) {
            float4 a4 = *(const float4*)&As[kk][ty * 4];
            float4 b4 = *(const float4*)&Bs[kk][tx * 4];
            float avr[4] = {a4.x, a4.y, a4.z, a4.w};
            float bvr[4] = {b4.x, b4.y, b4.z, b4.w};
#pragma unroll
            for (int i = 0; i < 4; ++i)
#pragma unroll
                for (int j = 0; j < 4; ++j)
                    acc[i][j] = fmaf(avr[i], bvr[j], acc[i][j]);
        }
    }
#pragma unroll
    for (int i = 0; i < 4; ++i) {
        int m = m0 + ty * 4 + i;
        if (m < 152) {
#pragma unroll
            for (int j = 0; j < 4; ++j)
                EW[(size_t)m * SIXH + n0 + tx * 4 + j] = acc[i][j];
        }
    }
}

// ---------------------------------------------------------------------------
// step_fused: 256 blocks x 1 batch row. Sums partials + bias, gates,
// c/h update, tiled bf16 h emit, pred (Wout L2-resident), argmax.
// ---------------------------------------------------------------------------
__global__ __launch_bounds__(256) void step_fused(
    const float* __restrict__ px_t,        // [256, 3072]
    const float* __restrict__ EW,          // [152, 3072]
    const float* __restrict__ partial,     // [4][256][2560]
    const float* __restrict__ b_state,     // [2560]
    const int*   __restrict__ commit_prev, // [256]
    int first,
    const float* __restrict__ Wout, const float* __restrict__ b_out,
    ushort_t* __restrict__ hHt, ushort_t* __restrict__ hLt,
    float* __restrict__ c,
    float* __restrict__ dists_t, int* __restrict__ commit_t)
{
    __shared__ float hs[HID];
    __shared__ float preds[NCLS + 1];

    const int tid = threadIdx.x;
    const int b   = blockIdx.x;
    const int erow = first ? 0 : (commit_prev[b] + 1);
    const float* ew = EW + (size_t)erow * SIXH;
    const float* px = px_t + (size_t)b * SIXH;
    const float* pp = partial + (size_t)b * FIVEH;

#pragma unroll
    for (int it = 0; it < 2; ++it) {
        const int u = it * 256 + tid;
        float p[6];
#pragma unroll
        for (int k2 = 0; k2 < 5; ++k2) {
            const int o = k2 * HID + u;
            float s = pp[o] + pp[256 * FIVEH + o]
                    + pp[2 * 256 * FIVEH + o] + pp[3 * 256 * FIVEH + o];
            p[k2] = px[o] + ew[o] + s + b_state[o];
        }
        p[5] = px[5 * HID + u] + ew[5 * HID + u];

        float i_g = sigmoidf(p[0]);
        float f_g = sigmoidf(p[1]);
        float m_i = tanhf(p[2]);
        float o_g = sigmoidf(p[3]);
        float c_new = i_g * m_i + f_g * c[(size_t)b * HID + u];
        float outv  = o_g * tanhf(c_new);
        float hw    = sigmoidf(p[4]);
        float h_new = hw * outv + (1.f - hw) * p[5];
        c[(size_t)b * HID + u] = c_new;
        hs[u] = h_new;
    }
    __syncthreads();

    // tiled bf16 h emit: tid<128 -> (hi/lo half, 8-elem chunk)
    if (tid < 128) {
        const int half = tid >> 6;
        const int ch   = tid & 63;
        const int mt   = b >> 7;
        const int row  = b & 127;
        const size_t off = ((size_t)(mt * NKT_H + (ch >> 2))) * 4096
                         + (size_t)(ch & 3) * 1024 + (size_t)row * 8;
        alignas(16) ushort_t buf[8];
        if (half == 0) {
#pragma unroll
            for (int e = 0; e < 8; ++e) buf[e] = f2bf_rn(hs[ch * 8 + e]);
            *(uint4*)(hHt + off) = *(const uint4*)buf;
        } else {
#pragma unroll
            for (int e = 0; e < 8; ++e) {
                float x = hs[ch * 8 + e];
                buf[e] = f2bf_rn(x - bf2f(f2bf_rn(x)));
            }
            *(uint4*)(hLt + off) = *(const uint4*)buf;
        }
    }

    if (tid < NCLS) {
        const float* w = Wout + (size_t)tid * HID;
        float s0 = 0.f, s1 = 0.f, s2 = 0.f, s3 = 0.f;
        for (int k = 0; k < HID; k += 4) {
            float4 w4 = *(const float4*)(w + k);
            float4 h4 = *(const float4*)&hs[k];
            s0 = fmaf(h4.x, w4.x, s0);
            s1 = fmaf(h4.y, w4.y, s1);
            s2 = fmaf(h4.z, w4.z, s2);
            s3 = fmaf(h4.w, w4.w, s3);
        }
        float s = b_out[tid] + ((s0 + s1) + (s2 + s3));
        preds[tid] = s;
        dists_t[(size_t)b * NCLS + tid] = s;
    }
    __syncthreads();

    if (tid == 0) {
        int   bi = 1;
        float bv = preds[1];
        for (int n = 2; n < NCLS; ++n) {
            float v = preds[n];
            if (v > bv) { bv = v; bi = n; }
        }
        commit_t[b] = bi;
    }
}

// ---------------------------------------------------------------------------
__global__ __launch_bounds__(192) void gather_out(
    const float* __restrict__ dists, const int* __restrict__ commits,
    const int* __restrict__ gidx, float* __restrict__ out)
{
    const int i = blockIdx.x;
    const int g = gidx[i];
    if (threadIdx.x < NCLS)
        out[(size_t)i * NCLS + threadIdx.x] = dists[(size_t)g * NCLS + threadIdx.x];
    if (threadIdx.x == NCLS)
        out[(size_t)NPACK * NCLS + i] = (float)commits[g];
}

// init: c = 0, tiled h hi/lo = 0 (so first ps partials == 0)
__global__ __launch_bounds__(256) void init_state(
    float* __restrict__ c, ushort_t* __restrict__ hHt, ushort_t* __restrict__ hLt)
{
    int i = blockIdx.x * 256 + threadIdx.x;
    if (i < BATCH * HID) { c[i] = 0.f; hHt[i] = 0; hLt[i] = 0; }
}

// ---------------------------------------------------------------------------
extern "C" void kernel_launch(void* const* d_in, const int* in_sizes, int n_in,
                              void* d_out, int out_size, void* d_ws, size_t ws_size,
                              hipStream_t stream)
{
    const float* X      = (const float*)d_in[0];  // [80,256,4936]
    const float* embed  = (const float*)d_in[1];  // [152,200]
    const float* Win    = (const float*)d_in[2];  // [3072,5136]
    const float* b_in   = (const float*)d_in[3];
    const float* Wst    = (const float*)d_in[4];  // [2560,512]
    const float* b_st   = (const float*)d_in[5];
    const float* Wout   = (const float*)d_in[6];  // [151,512]
    const float* b_out  = (const float*)d_in[7];
    const int*   gidx   = (const int*)d_in[8];

    const size_t WN  = (size_t)24 * NKT * 4096;    // ushorts per Win-split array
    const size_t WSN = (size_t)20 * NKT_H * 4096;  // ushorts per Wst-split array
    const size_t HN  = (size_t)2 * NKT_H * 4096;   // ushorts per h-split array

    ushort_t* Wh   = (ushort_t*)d_ws;
    ushort_t* Wl   = Wh + WN;
    ushort_t* WstH = Wl + WN;
    ushort_t* WstL = WstH + WSN;
    ushort_t* hHt  = WstL + WSN;
    ushort_t* hLt  = hHt + HN;
    float* EW      = (float*)(hLt + HN);
    float* partial = EW + (size_t)152 * SIXH;            // 4*256*2560
    float* c       = partial + (size_t)4 * BATCH * FIVEH;
    float* dists   = c + (size_t)BATCH * HID;
    int* commits   = (int*)(dists + (size_t)T_STEPS * BATCH * NCLS);
    char* cbase    = (char*)(commits + T_STEPS * BATCH);

    size_t off = (size_t)(cbase - (char*)d_ws);
    off = (off + 255) & ~(size_t)255;
    const size_t per_t = (size_t)2 * 2 * NKT * 4096 * 2 + (size_t)BATCH * SIXH * 4;
    size_t rem = (ws_size > off) ? (ws_size - off) : 0;
    int CT = (int)(rem / per_t);
    if (CT > T_STEPS) CT = T_STEPS;
    if (CT < 1) CT = 1;

    ushort_t* Xh = (ushort_t*)((char*)d_ws + off);
    ushort_t* Xl = Xh + (size_t)2 * CT * NKT * 4096;
    float* px    = (float*)(Xl + (size_t)2 * CT * NKT * 4096);

    // one-time prep
    convert_split<<<dim3(NKT, 24), 256, 0, stream>>>(Win, DE, DIM, Wh, Wl, NKT);
    convert_split<<<dim3(NKT_H, 20), 256, 0, stream>>>(Wst, HID, HID, WstH, WstL, NKT_H);
    ew_gemm<<<dim3(SIXH / 64, 3), 256, 0, stream>>>(embed, Win, EW);
    init_state<<<512, 256, 0, stream>>>(c, hHt, hLt);

    for (int t0 = 0; t0 < T_STEPS; t0 += CT) {
        int nt = T_STEPS - t0;
        if (nt > CT) nt = CT;
        convert_split<<<dim3(NKT, 2 * nt), 256, 0, stream>>>(
            X + (size_t)t0 * BATCH * DIM, DIM, DIM, Xh, Xl, NKT);
        const int nwg = (SIXH / 128) * (2 * nt);
        mfma3<<<nwg, 256, 0, stream>>>(
            Xh, Xl, Wh, Wl, b_in, px, NKT, SIXH, SIXH / 128, nwg);
        for (int t = t0; t < t0 + nt; ++t) {
            ps_splitk<<<dim3(40, 4, 4), 256, 0, stream>>>(
                hHt, hLt, WstH, WstL, partial);
            step_fused<<<BATCH, 256, 0, stream>>>(
                px + (size_t)(t - t0) * BATCH * SIXH, EW, partial, b_st,
                commits + (size_t)(t > 0 ? t - 1 : 0) * BATCH, (t == 0) ? 1 : 0,
                Wout, b_out, hHt, hLt, c,
                dists + (size_t)t * BATCH * NCLS, commits + (size_t)t * BATCH);
        }
    }

    gather_out<<<NPACK, 192, 0, stream>>>(dists, commits, gidx, (float*)d_out);
}